// Round 1
// baseline (12424.581 us; speedup 1.0000x reference)
//
#include <hip/hip_runtime.h>

#define NEG_SLOPE 0.01f

static inline int cdiv(long long a, long long b) { return (int)((a + b - 1) / b); }

__global__ __launch_bounds__(256) void zero_f32(float* __restrict__ p, int n) {
    int i = blockIdx.x * 256 + threadIdx.x;
    if (i < n) p[i] = 0.f;
}

// H[n,:] = act(in[n,:]) @ W[0:32,:] + b ;  Z[n,:] = act(in[n,:]) @ W[32:64,:]
// in/H/Z all stride-32 rows. W is row-major [64, COUT].
template<int CIN, int COUT, bool LRELU>
__global__ __launch_bounds__(256) void dense_kernel(
    const float* __restrict__ in, const float* __restrict__ W,
    const float* __restrict__ b, float* __restrict__ H,
    float* __restrict__ Z, int N)
{
    int n = blockIdx.x * 256 + threadIdx.x;
    if (n >= N) return;
    const float* row = in + (size_t)n * 32;
    float xv[CIN];
#pragma unroll
    for (int f = 0; f < CIN; f += 4) {
        float4 v = *(const float4*)(row + f);
        xv[f] = v.x; xv[f + 1] = v.y; xv[f + 2] = v.z; xv[f + 3] = v.w;
    }
    if (LRELU) {
#pragma unroll
        for (int f = 0; f < CIN; f++) xv[f] = xv[f] > 0.f ? xv[f] : NEG_SLOPE * xv[f];
    }
    float acct[COUT], accb[COUT];
#pragma unroll
    for (int c = 0; c < COUT; c++) { acct[c] = b[c]; accb[c] = 0.f; }
#pragma unroll 4
    for (int f = 0; f < CIN; f++) {
        float xf = xv[f];
#pragma unroll
        for (int c = 0; c < COUT; c++) {
            acct[c] = fmaf(xf, W[f * COUT + c], acct[c]);
            accb[c] = fmaf(xf, W[(CIN + f) * COUT + c], accb[c]);
        }
    }
    float* hrow = H + (size_t)n * 32;
    float* zrow = Z + (size_t)n * 32;
#pragma unroll
    for (int c = 0; c < COUT; c++) { hrow[c] = acct[c]; zrow[c] = accb[c]; }
}

// 8 threads per edge, 4 features each (C=32): H[rows[e],:] += vals[e] * Z[cols[e],:]
__global__ __launch_bounds__(256) void spmm_scatter32(
    const int* __restrict__ rows, const int* __restrict__ cols,
    const float* __restrict__ vals, const float* __restrict__ Z,
    float* __restrict__ H, int E)
{
    long long t = (long long)blockIdx.x * 256 + threadIdx.x;
    int e = (int)(t >> 3);
    int sub = (int)(t & 7);
    if (e >= E) return;
    int r = rows[e], c = cols[e];
    float v = vals[e];
    float4 z = *(const float4*)(Z + (size_t)c * 32 + sub * 4);
    float* hp = H + (size_t)r * 32 + sub * 4;
    atomicAdd(hp + 0, v * z.x);
    atomicAdd(hp + 1, v * z.y);
    atomicAdd(hp + 2, v * z.z);
    atomicAdd(hp + 3, v * z.w);
}

// 1 thread per edge, 10 features (layer 3)
__global__ __launch_bounds__(256) void spmm_scatter10(
    const int* __restrict__ rows, const int* __restrict__ cols,
    const float* __restrict__ vals, const float* __restrict__ Z,
    float* __restrict__ H, int E)
{
    int e = blockIdx.x * 256 + threadIdx.x;
    if (e >= E) return;
    int r = rows[e], c = cols[e];
    float v = vals[e];
    const float* zp = Z + (size_t)c * 32;
    float* hp = H + (size_t)r * 32;
#pragma unroll
    for (int f = 0; f < 10; f++) atomicAdd(hp + f, v * zp[f]);
}

// segment-sum H3[:, 0:10] by graph id + counts
__global__ __launch_bounds__(256) void pool_kernel(
    const float* __restrict__ H3, const int* __restrict__ batch,
    float* __restrict__ pool, float* __restrict__ cnt, int N, int dimoff)
{
    int n = blockIdx.x * 256 + threadIdx.x;
    if (n >= N) return;
    int g = batch[n];
    const float* hp = H3 + (size_t)n * 32;
    float* pp = pool + (size_t)g * 30 + dimoff;
#pragma unroll
    for (int f = 0; f < 10; f++) atomicAdd(pp + f, hp[f]);
    atomicAdd(cnt + g, 1.0f);
}

__global__ __launch_bounds__(256) void final_kernel(
    const float* __restrict__ pool, const float* __restrict__ cnt,
    const float* __restrict__ Wf, const float* __restrict__ bfv,
    float* __restrict__ out, int G)
{
    int g = blockIdx.x * 256 + threadIdx.x;
    if (g >= G) return;
    float m[30];
#pragma unroll
    for (int d = 0; d < 3; d++) {
        float c = cnt[(size_t)d * G + g];
        c = c > 1.f ? c : 1.f;
        float inv = 1.f / c;
#pragma unroll
        for (int f = 0; f < 10; f++) m[d * 10 + f] = pool[(size_t)g * 30 + d * 10 + f] * inv;
    }
    float lg[10];
#pragma unroll
    for (int o = 0; o < 10; o++) {
        float a = bfv[o];
#pragma unroll
        for (int j = 0; j < 30; j++) a = fmaf(m[j], Wf[j * 10 + o], a);
        lg[o] = a;
    }
    float mx = lg[0];
#pragma unroll
    for (int o = 1; o < 10; o++) mx = fmaxf(mx, lg[o]);
    float s = 0.f;
#pragma unroll
    for (int o = 0; o < 10; o++) { lg[o] = __expf(lg[o] - mx); s += lg[o]; }
    float invs = 1.f / s;
#pragma unroll
    for (int o = 0; o < 10; o++) out[(size_t)g * 10 + o] = lg[o] * invs;
}

extern "C" void kernel_launch(void* const* d_in, const int* in_sizes, int n_in,
                              void* d_out, int out_size, void* d_ws, size_t ws_size,
                              hipStream_t stream)
{
    (void)n_in; (void)ws_size;
    const float* x[3]    = {(const float*)d_in[0], (const float*)d_in[1], (const float*)d_in[2]};
    const float* vals[3] = {(const float*)d_in[3], (const float*)d_in[4], (const float*)d_in[5]};
    const int* rows[3]   = {(const int*)d_in[6], (const int*)d_in[8], (const int*)d_in[10]};
    const int* cols[3]   = {(const int*)d_in[7], (const int*)d_in[9], (const int*)d_in[11]};
    const int* batch[3]  = {(const int*)d_in[12], (const int*)d_in[13], (const int*)d_in[14]};
    const float* W1[3] = {(const float*)d_in[16], (const float*)d_in[22], (const float*)d_in[28]};
    const float* b1[3] = {(const float*)d_in[17], (const float*)d_in[23], (const float*)d_in[29]};
    const float* W2[3] = {(const float*)d_in[18], (const float*)d_in[24], (const float*)d_in[30]};
    const float* b2[3] = {(const float*)d_in[19], (const float*)d_in[25], (const float*)d_in[31]};
    const float* W3[3] = {(const float*)d_in[20], (const float*)d_in[26], (const float*)d_in[32]};
    const float* b3[3] = {(const float*)d_in[21], (const float*)d_in[27], (const float*)d_in[33]};
    const float* Wf  = (const float*)d_in[34];
    const float* bfv = (const float*)d_in[35];
    float* out = (float*)d_out;

    int N[3] = {in_sizes[0] / 32, in_sizes[1] / 32, in_sizes[2] / 32};
    int E[3] = {in_sizes[3], in_sizes[4], in_sizes[5]};
    int G = out_size / 10;
    int maxN = N[0]; if (N[1] > maxN) maxN = N[1]; if (N[2] > maxN) maxN = N[2];

    float* bufA = (float*)d_ws;
    float* bufB = bufA + (size_t)maxN * 32;
    float* bufZ = bufB + (size_t)maxN * 32;
    float* pool = bufZ + (size_t)maxN * 32;
    float* cnt  = pool + (size_t)G * 30;

    zero_f32<<<cdiv(G * 33, 256), 256, 0, stream>>>(pool, G * 33);

    for (int d = 0; d < 3; d++) {
        int n = N[d], e = E[d];
        // layer 1: input x (no activation)
        dense_kernel<32, 32, false><<<cdiv(n, 256), 256, 0, stream>>>(x[d], W1[d], b1[d], bufA, bufZ, n);
        spmm_scatter32<<<cdiv((long long)e * 8, 256), 256, 0, stream>>>(rows[d], cols[d], vals[d], bufZ, bufA, e);
        // layer 2: leaky_relu on input
        dense_kernel<32, 32, true><<<cdiv(n, 256), 256, 0, stream>>>(bufA, W2[d], b2[d], bufB, bufZ, n);
        spmm_scatter32<<<cdiv((long long)e * 8, 256), 256, 0, stream>>>(rows[d], cols[d], vals[d], bufZ, bufB, e);
        // layer 3: leaky_relu on input, 10 outputs
        dense_kernel<32, 10, true><<<cdiv(n, 256), 256, 0, stream>>>(bufB, W3[d], b3[d], bufA, bufZ, n);
        spmm_scatter10<<<cdiv(e, 256), 256, 0, stream>>>(rows[d], cols[d], vals[d], bufZ, bufA, e);
        // mean-pool partials
        pool_kernel<<<cdiv(n, 256), 256, 0, stream>>>(bufA, batch[d], pool, cnt + (size_t)d * G, n, d * 10);
    }
    final_kernel<<<cdiv(G, 256), 256, 0, stream>>>(pool, cnt, Wf, bfv, out, G);
}

// Round 2
// 2045.568 us; speedup vs baseline: 6.0739x; 6.0739x over previous
//
#include <hip/hip_runtime.h>

#define NEG_SLOPE 0.01f
#define SCAN_TILE 4096

static inline int cdiv(long long a, long long b) { return (int)((a + b - 1) / b); }

__global__ __launch_bounds__(256) void zero_i32(int* __restrict__ p, int n) {
    int i = blockIdx.x * 256 + threadIdx.x;
    if (i < n) p[i] = 0;
}

__global__ __launch_bounds__(256) void hist_rows(const int* __restrict__ rows, int* __restrict__ cnt, int E) {
    int e = blockIdx.x * 256 + threadIdx.x;
    if (e < E) atomicAdd(&cnt[rows[e]], 1);
}

// block-sum of 4096-int tiles
__global__ __launch_bounds__(256) void scan1(const int* __restrict__ cnt, int* __restrict__ bsums, int N) {
    __shared__ int sd[256];
    int base = blockIdx.x * SCAN_TILE + threadIdx.x * 16;
    int s = 0;
#pragma unroll
    for (int k = 0; k < 16; k++) { int i = base + k; if (i < N) s += cnt[i]; }
    sd[threadIdx.x] = s; __syncthreads();
    for (int off = 128; off > 0; off >>= 1) {
        if (threadIdx.x < (unsigned)off) sd[threadIdx.x] += sd[threadIdx.x + off];
        __syncthreads();
    }
    if (threadIdx.x == 0) bsums[blockIdx.x] = sd[0];
}

// sequential exclusive scan of block sums (nb <= ~100)
__global__ void scan2(int* __restrict__ bsums, int nb) {
    if (threadIdx.x == 0 && blockIdx.x == 0) {
        int run = 0;
        for (int i = 0; i < nb; i++) { int v = bsums[i]; bsums[i] = run; run += v; }
    }
}

// writes exclusive scan to rowptr[i] and pos[i] (pos aliases cnt, rewritten in place)
__global__ __launch_bounds__(256) void scan3(int* __restrict__ cnt_pos, int* __restrict__ rowptr,
                                             const int* __restrict__ bsums, int N, int E) {
    __shared__ int sd[256];
    int t = threadIdx.x;
    int base = blockIdx.x * SCAN_TILE + t * 16;
    int v[16]; int s = 0;
#pragma unroll
    for (int k = 0; k < 16; k++) { int i = base + k; v[k] = (i < N) ? cnt_pos[i] : 0; s += v[k]; }
    sd[t] = s; __syncthreads();
    for (int off = 1; off < 256; off <<= 1) {
        int x = (t >= off) ? sd[t - off] : 0;
        __syncthreads();
        sd[t] += x;
        __syncthreads();
    }
    int excl = sd[t] - s + bsums[blockIdx.x];
#pragma unroll
    for (int k = 0; k < 16; k++) {
        int i = base + k;
        if (i < N) { rowptr[i] = excl; cnt_pos[i] = excl; excl += v[k]; }
    }
    if (blockIdx.x == 0 && t == 0) rowptr[N] = E;
}

__global__ __launch_bounds__(256) void fill_csr(const int* __restrict__ rows, const int* __restrict__ cols,
                                                const float* __restrict__ vals, int* __restrict__ pos,
                                                int* __restrict__ scol, float* __restrict__ sval, int E) {
    int e = blockIdx.x * 256 + threadIdx.x;
    if (e >= E) return;
    int p = atomicAdd(&pos[rows[e]], 1);
    scol[p] = cols[e];
    sval[p] = vals[e];
}

// H[n,:] = act(in[n,:]) @ W[0:32,:] + b ;  Z[n,:] = act(in[n,:]) @ W[32:64,:]
// in/H may alias (in-place): each thread reads its row fully before writing.
template<int COUT, bool LRELU>
__global__ __launch_bounds__(256) void dense_kernel(
    const float* in, const float* __restrict__ W,
    const float* __restrict__ b, float* H,
    float* __restrict__ Z, int N)
{
    int n = blockIdx.x * 256 + threadIdx.x;
    if (n >= N) return;
    const float* row = in + (size_t)n * 32;
    float xv[32];
#pragma unroll
    for (int f = 0; f < 32; f += 4) {
        float4 v = *(const float4*)(row + f);
        xv[f] = v.x; xv[f + 1] = v.y; xv[f + 2] = v.z; xv[f + 3] = v.w;
    }
    if (LRELU) {
#pragma unroll
        for (int f = 0; f < 32; f++) xv[f] = xv[f] > 0.f ? xv[f] : NEG_SLOPE * xv[f];
    }
    float acct[COUT], accb[COUT];
#pragma unroll
    for (int c = 0; c < COUT; c++) { acct[c] = b[c]; accb[c] = 0.f; }
#pragma unroll 4
    for (int f = 0; f < 32; f++) {
        float xf = xv[f];
#pragma unroll
        for (int c = 0; c < COUT; c++) {
            acct[c] = fmaf(xf, W[f * COUT + c], acct[c]);
            accb[c] = fmaf(xf, W[(32 + f) * COUT + c], accb[c]);
        }
    }
    float* hrow = H + (size_t)n * 32;
    float* zrow = Z + (size_t)n * 32;
#pragma unroll
    for (int c = 0; c < COUT; c++) { hrow[c] = acct[c]; zrow[c] = accb[c]; }
}

// conflict-free CSR gather: H[r,:] += sum_e val[e] * Z[col[e],:]  (C=32, 8 lanes x float4)
__global__ __launch_bounds__(256) void gather32(
    const int* __restrict__ rowptr, const int* __restrict__ scol,
    const float* __restrict__ sval, const float* __restrict__ Z,
    float* __restrict__ H, int N)
{
    int tid = blockIdx.x * 256 + threadIdx.x;
    int row = tid >> 3, lane = tid & 7;
    if (row >= N) return;
    int s = rowptr[row], e = rowptr[row + 1];
    float ax = 0.f, ay = 0.f, az = 0.f, aw = 0.f;
    for (int i = s; i < e; i++) {
        int c = scol[i];
        float v = sval[i];
        float4 z = *(const float4*)(Z + (size_t)c * 32 + lane * 4);
        ax = fmaf(v, z.x, ax); ay = fmaf(v, z.y, ay);
        az = fmaf(v, z.z, az); aw = fmaf(v, z.w, aw);
    }
    float4* hp = (float4*)(H + (size_t)row * 32 + lane * 4);
    float4 h = *hp;
    h.x += ax; h.y += ay; h.z += az; h.w += aw;
    *hp = h;
}

// C=10: 8 lanes per row, lanes 0..4 each handle a float2
__global__ __launch_bounds__(256) void gather10(
    const int* __restrict__ rowptr, const int* __restrict__ scol,
    const float* __restrict__ sval, const float* __restrict__ Z,
    float* __restrict__ H, int N)
{
    int tid = blockIdx.x * 256 + threadIdx.x;
    int row = tid >> 3, lane = tid & 7;
    if (row >= N || lane >= 5) return;
    int s = rowptr[row], e = rowptr[row + 1];
    float ax = 0.f, ay = 0.f;
    for (int i = s; i < e; i++) {
        int c = scol[i];
        float v = sval[i];
        float2 z = *(const float2*)(Z + (size_t)c * 32 + lane * 2);
        ax = fmaf(v, z.x, ax); ay = fmaf(v, z.y, ay);
    }
    float* hp = H + (size_t)row * 32 + lane * 2;
    hp[0] += ax; hp[1] += ay;
}

// one block per graph; batch is sorted -> binary search node range, no atomics
__global__ __launch_bounds__(256) void pool_graph(
    const float* __restrict__ H, const int* __restrict__ batch,
    float* __restrict__ pool, int N, int dimoff)
{
    int g = blockIdx.x;
    int lo = 0, hi = N;
    while (lo < hi) { int mid = (lo + hi) >> 1; if (batch[mid] < g) lo = mid + 1; else hi = mid; }
    int start = lo;
    lo = start; hi = N;
    while (lo < hi) { int mid = (lo + hi) >> 1; if (batch[mid] < g + 1) lo = mid + 1; else hi = mid; }
    int end = lo;
    int t = threadIdx.x, f = t & 15, chain = t >> 4;
    __shared__ float sd[256];
    float acc = 0.f;
    if (f < 10) {
        for (int i = start + chain; i < end; i += 16) acc += H[(size_t)i * 32 + f];
    }
    sd[t] = acc; __syncthreads();
    if (chain == 0 && f < 10) {
        float s = 0.f;
#pragma unroll
        for (int k = 0; k < 16; k++) s += sd[k * 16 + f];
        int c = end - start;
        float inv = 1.f / (float)(c > 1 ? c : 1);
        pool[(size_t)g * 30 + dimoff + f] = s * inv;
    }
}

__global__ __launch_bounds__(256) void final_kernel(
    const float* __restrict__ pool, const float* __restrict__ Wf,
    const float* __restrict__ bfv, float* __restrict__ out, int G)
{
    int g = blockIdx.x * 256 + threadIdx.x;
    if (g >= G) return;
    float m[30];
#pragma unroll
    for (int j = 0; j < 30; j++) m[j] = pool[(size_t)g * 30 + j];
    float lg[10];
#pragma unroll
    for (int o = 0; o < 10; o++) {
        float a = bfv[o];
#pragma unroll
        for (int j = 0; j < 30; j++) a = fmaf(m[j], Wf[j * 10 + o], a);
        lg[o] = a;
    }
    float mx = lg[0];
#pragma unroll
    for (int o = 1; o < 10; o++) mx = fmaxf(mx, lg[o]);
    float s = 0.f;
#pragma unroll
    for (int o = 0; o < 10; o++) { lg[o] = __expf(lg[o] - mx); s += lg[o]; }
    float invs = 1.f / s;
#pragma unroll
    for (int o = 0; o < 10; o++) out[(size_t)g * 10 + o] = lg[o] * invs;
}

extern "C" void kernel_launch(void* const* d_in, const int* in_sizes, int n_in,
                              void* d_out, int out_size, void* d_ws, size_t ws_size,
                              hipStream_t stream)
{
    (void)n_in; (void)ws_size;
    const float* x[3]    = {(const float*)d_in[0], (const float*)d_in[1], (const float*)d_in[2]};
    const float* vals[3] = {(const float*)d_in[3], (const float*)d_in[4], (const float*)d_in[5]};
    const int* rows[3]   = {(const int*)d_in[6], (const int*)d_in[8], (const int*)d_in[10]};
    const int* cols[3]   = {(const int*)d_in[7], (const int*)d_in[9], (const int*)d_in[11]};
    const int* batch[3]  = {(const int*)d_in[12], (const int*)d_in[13], (const int*)d_in[14]};
    const float* W1[3] = {(const float*)d_in[16], (const float*)d_in[22], (const float*)d_in[28]};
    const float* b1[3] = {(const float*)d_in[17], (const float*)d_in[23], (const float*)d_in[29]};
    const float* W2[3] = {(const float*)d_in[18], (const float*)d_in[24], (const float*)d_in[30]};
    const float* b2[3] = {(const float*)d_in[19], (const float*)d_in[25], (const float*)d_in[31]};
    const float* W3[3] = {(const float*)d_in[20], (const float*)d_in[26], (const float*)d_in[32]};
    const float* b3[3] = {(const float*)d_in[21], (const float*)d_in[27], (const float*)d_in[33]};
    const float* Wf  = (const float*)d_in[34];
    const float* bfv = (const float*)d_in[35];
    float* out = (float*)d_out;

    int N[3] = {in_sizes[0] / 32, in_sizes[1] / 32, in_sizes[2] / 32};
    int E[3] = {in_sizes[3], in_sizes[4], in_sizes[5]};
    int G = out_size / 10;
    int maxN = N[0]; if (N[1] > maxN) maxN = N[1]; if (N[2] > maxN) maxN = N[2];
    int maxE = E[0]; if (E[1] > maxE) maxE = E[1]; if (E[2] > maxE) maxE = E[2];

    float* bufA  = (float*)d_ws;
    float* bufZ  = bufA + (size_t)maxN * 32;
    float* pool  = bufZ + (size_t)maxN * 32;
    float* svalp = pool + (size_t)G * 30;
    int*   scol  = (int*)(svalp + maxE);
    int*   rowptr= scol + maxE;
    int*   pos   = rowptr + (maxN + 1);
    int*   bsums = pos + maxN;

    for (int d = 0; d < 3; d++) {
        int n = N[d], e = E[d];
        int nb = cdiv(n, SCAN_TILE);
        // --- build CSR for this branch (row order reused by all 3 layers) ---
        zero_i32<<<cdiv(n, 256), 256, 0, stream>>>(pos, n);
        hist_rows<<<cdiv(e, 256), 256, 0, stream>>>(rows[d], pos, e);
        scan1<<<nb, 256, 0, stream>>>(pos, bsums, n);
        scan2<<<1, 64, 0, stream>>>(bsums, nb);
        scan3<<<nb, 256, 0, stream>>>(pos, rowptr, bsums, n, e);
        fill_csr<<<cdiv(e, 256), 256, 0, stream>>>(rows[d], cols[d], vals[d], pos, scol, svalp, e);
        // --- 3 layers, scatter replaced by conflict-free gather ---
        dense_kernel<32, false><<<cdiv(n, 256), 256, 0, stream>>>(x[d], W1[d], b1[d], bufA, bufZ, n);
        gather32<<<cdiv((long long)n * 8, 256), 256, 0, stream>>>(rowptr, scol, svalp, bufZ, bufA, n);
        dense_kernel<32, true><<<cdiv(n, 256), 256, 0, stream>>>(bufA, W2[d], b2[d], bufA, bufZ, n);
        gather32<<<cdiv((long long)n * 8, 256), 256, 0, stream>>>(rowptr, scol, svalp, bufZ, bufA, n);
        dense_kernel<10, true><<<cdiv(n, 256), 256, 0, stream>>>(bufA, W3[d], b3[d], bufA, bufZ, n);
        gather10<<<cdiv((long long)n * 8, 256), 256, 0, stream>>>(rowptr, scol, svalp, bufZ, bufA, n);
        pool_graph<<<G, 256, 0, stream>>>(bufA, batch[d], pool, n, d * 10);
    }
    final_kernel<<<cdiv(G, 256), 256, 0, stream>>>(pool, Wf, bfv, out, G);
}